// Round 5
// baseline (55.164 us; speedup 1.0000x reference)
//
#include <hip/hip_runtime.h>

#define B_    4
#define N_    1024
#define FIN   128
#define FOUT  256
#define NH    8
#define ND    32
#define NSL   0.2f
#define LOG2E 1.44269504088896340736f

typedef _Float16 half8 __attribute__((ext_vector_type(8)));
typedef __fp16 fp16x2 __attribute__((ext_vector_type(2)));
typedef float f32x4 __attribute__((ext_vector_type(4)));

// ---- K1: g16T[hb][f][n] = f16(h@W); elt/ert[hb][n] = LOG2E*(g.a_l / g.a_r) ----
// 128 threads, 8 rows/block, 2 cols/thread. LDS h read as b128 (4k per read):
// LDS cost 8 b128 per 4k-chunk vs 64 FMA -> VALU-balanced (round-2 version was
// 8 ds_read_b32 per 8 FMA = LDS-throughput-bound at ~15us).
__global__ __launch_bounds__(128) void gat_k1(
    const float* __restrict__ h, const float* __restrict__ W,
    const float* __restrict__ a_vec, _Float16* __restrict__ g16,
    float* __restrict__ elt, float* __restrict__ ert)
{
  __shared__ float hs[8][FIN];   // 4 KB
  const int t = threadIdx.x;     // 0..127
  const int row0 = blockIdx.x * 8;

  {
    const float4* src = (const float4*)(h + (size_t)row0 * FIN);
    float4* dst = (float4*)&hs[0][0];
    dst[t]       = src[t];
    dst[t + 128] = src[t + 128];
  }
  __syncthreads();

  const int c0 = 2 * t;          // cols c0, c0+1 (never straddles a head: 2|32)
  float acc0[8] = {0.f,0.f,0.f,0.f,0.f,0.f,0.f,0.f};
  float acc1[8] = {0.f,0.f,0.f,0.f,0.f,0.f,0.f,0.f};

#pragma unroll 4
  for (int k4 = 0; k4 < FIN; k4 += 4) {
    const float2 w0 = *(const float2*)&W[(k4 + 0) * FOUT + c0];
    const float2 w1 = *(const float2*)&W[(k4 + 1) * FOUT + c0];
    const float2 w2 = *(const float2*)&W[(k4 + 2) * FOUT + c0];
    const float2 w3 = *(const float2*)&W[(k4 + 3) * FOUT + c0];
#pragma unroll
    for (int r = 0; r < 8; ++r) {
      const float4 hv = *(const float4*)&hs[r][k4];   // broadcast b128
      acc0[r] += hv.x * w0.x + hv.y * w1.x + hv.z * w2.x + hv.w * w3.x;
      acc1[r] += hv.x * w0.y + hv.y * w1.y + hv.z * w2.y + hv.w * w3.y;
    }
  }

  const int f0 = c0 & 31, head = c0 >> 5;
  const int b = row0 >> 10, n0 = row0 & 1023;
  const int hb = b * NH + head;

  half8 hv0, hv1;
#pragma unroll
  for (int r = 0; r < 8; ++r) { hv0[r] = (_Float16)acc0[r]; hv1[r] = (_Float16)acc1[r]; }
  *(half8*)&g16[((size_t)hb * ND + f0) * N_ + n0]     = hv0;
  *(half8*)&g16[((size_t)hb * ND + f0 + 1) * N_ + n0] = hv1;

  const float al0 = a_vec[f0] * LOG2E,      al1 = a_vec[f0 + 1] * LOG2E;
  const float ar0 = a_vec[ND + f0] * LOG2E, ar1 = a_vec[ND + f0 + 1] * LOG2E;
#pragma unroll
  for (int r = 0; r < 8; ++r) {
    float pl = acc0[r] * al0 + acc1[r] * al1;
    float pr = acc0[r] * ar0 + acc1[r] * ar1;
#pragma unroll
    for (int m = 8; m >= 1; m >>= 1) {
      pl += __shfl_xor(pl, m, 16);
      pr += __shfl_xor(pr, m, 16);
    }
    if ((t & 15) == 0) {
      elt[(size_t)hb * N_ + n0 + r] = pl;
      ert[(size_t)hb * N_ + n0 + r] = pr;
    }
  }
}

// ---- K3: block = (b, head, 16-row i-tile); 4 waves each: 16 i x 32 f x 256 j ----
// jt loop FULLY unrolled -> straight-line block, scheduler hoists all 32 VMEM
// loads into flight (round-2/3 compiled at VGPR=20: zero hoisting, latency-bound).
__global__ __launch_bounds__(256) void gat_k3(
    const int* __restrict__ adj, const _Float16* __restrict__ g16,
    const float* __restrict__ elt, const float* __restrict__ ert,
    float* __restrict__ out)
{
  __shared__ float er_s[N_];
  __shared__ float dpart[4][32][17];
  __shared__ float denp[4][16];

  const int t = threadIdx.x;
  const int it   = blockIdx.x & 63;
  const int head = (blockIdx.x >> 6) & 7;
  const int b    = blockIdx.x >> 9;
  const int i0   = it * 16;
  const int hb   = b * NH + head;

  *(float4*)&er_s[4 * t] = *(const float4*)&ert[(size_t)hb * N_ + 4 * t];
  __syncthreads();

  const int wv = t >> 6, lane = t & 63;
  const int li = lane & 15, kg = lane >> 4;

  const float el_i = elt[(size_t)hb * N_ + i0 + li];
  const int* __restrict__ adjrow =
      adj + ((size_t)(b * N_ + i0 + li)) * N_ + wv * 256 + kg * 8;
  const _Float16* __restrict__ arow0 =
      g16 + ((size_t)hb * ND + li) * N_ + wv * 256 + kg * 8;
  const _Float16* __restrict__ arow1 = arow0 + (size_t)16 * N_;

  f32x4 acc0 = {0.f, 0.f, 0.f, 0.f};
  f32x4 acc1 = {0.f, 0.f, 0.f, 0.f};
  f32x4 accd = {0.f, 0.f, 0.f, 0.f};
  const half8 ones = {(_Float16)1.f, (_Float16)1.f, (_Float16)1.f, (_Float16)1.f,
                      (_Float16)1.f, (_Float16)1.f, (_Float16)1.f, (_Float16)1.f};

#pragma unroll
  for (int jt = 0; jt < 8; ++jt) {
    const int k0 = jt * 32;
    const int4 a0 = *(const int4*)(adjrow + k0);
    const int4 a1 = *(const int4*)(adjrow + k0 + 4);
    const int ks = wv * 256 + k0 + kg * 8;
    const float4 e0 = *(const float4*)&er_s[ks];
    const float4 e1 = *(const float4*)&er_s[ks + 4];
    const half8 Ag0 = *(const half8*)(arow0 + k0);
    const half8 Ag1 = *(const half8*)(arow1 + k0);

    const int   am[8]  = {a0.x, a0.y, a0.z, a0.w, a1.x, a1.y, a1.z, a1.w};
    const float er8[8] = {e0.x, e0.y, e0.z, e0.w, e1.x, e1.y, e1.z, e1.w};
    float pv[8];
#pragma unroll
    for (int e = 0; e < 8; ++e) {
      float x = el_i + er8[e];            // already log2-scaled
      x = fmaxf(x, NSL * x);              // LeakyReLU (scale>0 commutes)
      float p;
      asm("v_exp_f32 %0, %1" : "=v"(p) : "v"(x));  // 2^x
      pv[e] = am[e] ? p : 0.f;
    }

    union { half8 h8; unsigned u[4]; } P;
#pragma unroll
    for (int q = 0; q < 4; ++q) {
      union { fp16x2 h; unsigned u; } cv;
      cv.h = __builtin_amdgcn_cvt_pkrtz(pv[2 * q], pv[2 * q + 1]);
      P.u[q] = cv.u;
    }

    acc0 = __builtin_amdgcn_mfma_f32_16x16x32_f16(Ag0, P.h8, acc0, 0, 0, 0);
    acc1 = __builtin_amdgcn_mfma_f32_16x16x32_f16(Ag1, P.h8, acc1, 0, 0, 0);
    accd = __builtin_amdgcn_mfma_f32_16x16x32_f16(ones, P.h8, accd, 0, 0, 0);
  }

  // stash partials: D rows f = 4*kg + r (+16 for acc1), col i = li; den replicated
#pragma unroll
  for (int r = 0; r < 4; ++r) {
    dpart[wv][4 * kg + r][li]      = acc0[r];
    dpart[wv][16 + 4 * kg + r][li] = acc1[r];
  }
  if (lane < 16) denp[wv][lane] = accd[0];
  __syncthreads();

  // combine 4 j-partials, normalize, LeakyReLU, store
  for (int o = t; o < 512; o += 256) {
    const int f = o & 31, ii = o >> 5;
    const float s  = dpart[0][f][ii] + dpart[1][f][ii]
                   + dpart[2][f][ii] + dpart[3][f][ii];
    const float dn = denp[0][ii] + denp[1][ii] + denp[2][ii] + denp[3][ii];
    float v = s / dn;
    v = fmaxf(v, NSL * v);
    out[((size_t)(b * N_ + i0 + ii)) * FOUT + head * ND + f] = v;
  }
}

extern "C" void kernel_launch(void* const* d_in, const int* in_sizes, int n_in,
                              void* d_out, int out_size, void* d_ws, size_t ws_size,
                              hipStream_t stream) {
  const float* h     = (const float*)d_in[0];
  const int*   adj   = (const int*)d_in[1];
  const float* W     = (const float*)d_in[2];
  const float* a_vec = (const float*)d_in[3];
  float* out = (float*)d_out;

  _Float16* g16 = (_Float16*)d_ws;                         // B*NH*ND*N halves (2 MB)
  float* elt = (float*)(g16 + (size_t)B_ * NH * ND * N_);  // 32768 f
  float* ert = elt + (size_t)B_ * NH * N_;                 // 32768 f

  gat_k1<<<(B_ * N_) / 8, 128, 0, stream>>>(h, W, a_vec, g16, elt, ert);
  gat_k3<<<B_ * NH * (N_ / 16), 256, 0, stream>>>(adj, g16, elt, ert, out);
}

// Round 6
// 54.588 us; speedup vs baseline: 1.0106x; 1.0106x over previous
//
#include <hip/hip_runtime.h>

#define B_    4
#define N_    1024
#define FIN   128
#define FOUT  256
#define NH    8
#define ND    32
#define NSL   0.2f
#define LOG2E 1.44269504088896340736f

typedef _Float16 half8 __attribute__((ext_vector_type(8)));
typedef __fp16 fp16x2 __attribute__((ext_vector_type(2)));
typedef float f32x4 __attribute__((ext_vector_type(4)));

// ---- K1: g16T[hb][f][n] = f16(h@W); elt/ert[hb][n] = LOG2E*(g.a_l / g.a_r) ----
// 256 threads, 16 rows/block, 2 cols/thread. hs reads are wave-uniform b128
// broadcasts (free); W float2 loads are 512B-coalesced per wave.
__global__ __launch_bounds__(256) void gat_k1(
    const float* __restrict__ h, const float* __restrict__ W,
    const float* __restrict__ a_vec, _Float16* __restrict__ g16,
    float* __restrict__ elt, float* __restrict__ ert)
{
  __shared__ float hs[16][FIN];   // 8 KB
  const int t = threadIdx.x;
  const int row0 = blockIdx.x * 16;

  {
    const float4* src = (const float4*)(h + (size_t)row0 * FIN);
    float4* dst = (float4*)&hs[0][0];
    dst[t]       = src[t];
    dst[t + 256] = src[t + 256];
  }
  __syncthreads();

  const int cp = t & 127;          // col-pair id: cols 2cp, 2cp+1
  const int c0 = 2 * cp;
  const int r0 = (t >> 7) * 8;     // row-half: 0..7 or 8..15
  float acc0[8] = {0.f,0.f,0.f,0.f,0.f,0.f,0.f,0.f};
  float acc1[8] = {0.f,0.f,0.f,0.f,0.f,0.f,0.f,0.f};

#pragma unroll 4
  for (int k4 = 0; k4 < FIN; k4 += 4) {
    const float2 w0 = *(const float2*)&W[(k4 + 0) * FOUT + c0];
    const float2 w1 = *(const float2*)&W[(k4 + 1) * FOUT + c0];
    const float2 w2 = *(const float2*)&W[(k4 + 2) * FOUT + c0];
    const float2 w3 = *(const float2*)&W[(k4 + 3) * FOUT + c0];
#pragma unroll
    for (int r = 0; r < 8; ++r) {
      const float4 hv = *(const float4*)&hs[r0 + r][k4];   // broadcast
      acc0[r] += hv.x * w0.x + hv.y * w1.x + hv.z * w2.x + hv.w * w3.x;
      acc1[r] += hv.x * w0.y + hv.y * w1.y + hv.z * w2.y + hv.w * w3.y;
    }
  }

  const int f0 = c0 & 31, head = c0 >> 5;
  const int b = row0 >> 10, n0 = row0 & 1023;
  const int hb = b * NH + head;

  half8 hv0, hv1;
#pragma unroll
  for (int r = 0; r < 8; ++r) { hv0[r] = (_Float16)acc0[r]; hv1[r] = (_Float16)acc1[r]; }
  *(half8*)&g16[((size_t)hb * ND + f0) * N_ + n0 + r0]     = hv0;
  *(half8*)&g16[((size_t)hb * ND + f0 + 1) * N_ + n0 + r0] = hv1;

  const float al0 = a_vec[f0] * LOG2E,      al1 = a_vec[f0 + 1] * LOG2E;
  const float ar0 = a_vec[ND + f0] * LOG2E, ar1 = a_vec[ND + f0 + 1] * LOG2E;
#pragma unroll
  for (int r = 0; r < 8; ++r) {
    float pl = acc0[r] * al0 + acc1[r] * al1;
    float pr = acc0[r] * ar0 + acc1[r] * ar1;
#pragma unroll
    for (int m = 8; m >= 1; m >>= 1) {
      pl += __shfl_xor(pl, m, 16);
      pr += __shfl_xor(pr, m, 16);
    }
    if ((t & 15) == 0) {
      elt[(size_t)hb * N_ + n0 + r0 + r] = pl;
      ert[(size_t)hb * N_ + n0 + r0 + r] = pr;
    }
  }
}

// one 32-j sub-chunk: P-gen + 3 MFMA, operands from prefetched registers
#define COMPUTE4(A0v, A1v, G0v, G1v, KB)                                        \
  _Pragma("unroll")                                                             \
  for (int u = 0; u < 4; ++u) {                                                 \
    const int ks = wv * 256 + (KB) + u * 32 + kg * 8;                           \
    const float4 e0 = *(const float4*)&er_s[ks];                                \
    const float4 e1 = *(const float4*)&er_s[ks + 4];                            \
    const int   am[8]  = {A0v[u].x, A0v[u].y, A0v[u].z, A0v[u].w,               \
                          A1v[u].x, A1v[u].y, A1v[u].z, A1v[u].w};              \
    const float er8[8] = {e0.x, e0.y, e0.z, e0.w, e1.x, e1.y, e1.z, e1.w};      \
    float pv[8];                                                                \
    _Pragma("unroll")                                                           \
    for (int e = 0; e < 8; ++e) {                                               \
      float x = el_i + er8[e];                                                  \
      x = fmaxf(x, NSL * x);                                                    \
      float p;                                                                  \
      asm("v_exp_f32 %0, %1" : "=v"(p) : "v"(x));                               \
      pv[e] = am[e] ? p : 0.f;                                                  \
    }                                                                           \
    union { half8 h8; unsigned uu[4]; } P;                                      \
    _Pragma("unroll")                                                           \
    for (int q = 0; q < 4; ++q) {                                               \
      union { fp16x2 hh; unsigned uu; } cv;                                     \
      cv.hh = __builtin_amdgcn_cvt_pkrtz(pv[2 * q], pv[2 * q + 1]);             \
      P.uu[q] = cv.uu;                                                          \
    }                                                                           \
    acc0 = __builtin_amdgcn_mfma_f32_16x16x32_f16(G0v[u], P.h8, acc0, 0, 0, 0); \
    acc1 = __builtin_amdgcn_mfma_f32_16x16x32_f16(G1v[u], P.h8, acc1, 0, 0, 0); \
    accd = __builtin_amdgcn_mfma_f32_16x16x32_f16(ones, P.h8, accd, 0, 0, 0);   \
  }

// ---- K3: block = (b, head, 16-row i-tile); 4 waves each: 16 i x 32 f x 256 j ----
// Explicit 2-batch register prefetch (named arrays, static indices) +
// __launch_bounds__(256,2) to raise the VGPR budget to ~128 so the scheduler
// keeps the loads in flight (round-2 compiled at VGPR=20: load->wait->compute
// serialization, 34% VALU duty — THE bottleneck rounds 2-5).
__global__ __launch_bounds__(256, 2) void gat_k3(
    const int* __restrict__ adj, const _Float16* __restrict__ g16,
    const float* __restrict__ elt, const float* __restrict__ ert,
    float* __restrict__ out)
{
  __shared__ float er_s[N_];
  __shared__ float dpart[4][32][17];
  __shared__ float denp[4][16];

  const int t = threadIdx.x;
  const int it   = blockIdx.x & 63;
  const int head = (blockIdx.x >> 6) & 7;
  const int b    = blockIdx.x >> 9;
  const int i0   = it * 16;
  const int hb   = b * NH + head;

  *(float4*)&er_s[4 * t] = *(const float4*)&ert[(size_t)hb * N_ + 4 * t];
  __syncthreads();

  const int wv = t >> 6, lane = t & 63;
  const int li = lane & 15, kg = lane >> 4;

  const float el_i = elt[(size_t)hb * N_ + i0 + li];
  const int* __restrict__ adjrow =
      adj + ((size_t)(b * N_ + i0 + li)) * N_ + wv * 256 + kg * 8;
  const _Float16* __restrict__ arow0 =
      g16 + ((size_t)hb * ND + li) * N_ + wv * 256 + kg * 8;
  const _Float16* __restrict__ arow1 = arow0 + (size_t)16 * N_;

  f32x4 acc0 = {0.f, 0.f, 0.f, 0.f};
  f32x4 acc1 = {0.f, 0.f, 0.f, 0.f};
  f32x4 accd = {0.f, 0.f, 0.f, 0.f};
  const half8 ones = {(_Float16)1.f, (_Float16)1.f, (_Float16)1.f, (_Float16)1.f,
                      (_Float16)1.f, (_Float16)1.f, (_Float16)1.f, (_Float16)1.f};

  // prefetch batch A (j 0..127) and batch B (j 128..255): 32 loads in flight
  int4 Aa0[4], Aa1[4]; half8 Ga0[4], Ga1[4];
  int4 Ab0[4], Ab1[4]; half8 Gb0[4], Gb1[4];
#pragma unroll
  for (int u = 0; u < 4; ++u) {
    const int k0 = u * 32;
    Aa0[u] = *(const int4*)(adjrow + k0);
    Aa1[u] = *(const int4*)(adjrow + k0 + 4);
    Ga0[u] = *(const half8*)(arow0 + k0);
    Ga1[u] = *(const half8*)(arow1 + k0);
  }
#pragma unroll
  for (int u = 0; u < 4; ++u) {
    const int k0 = 128 + u * 32;
    Ab0[u] = *(const int4*)(adjrow + k0);
    Ab1[u] = *(const int4*)(adjrow + k0 + 4);
    Gb0[u] = *(const half8*)(arow0 + k0);
    Gb1[u] = *(const half8*)(arow1 + k0);
  }

  COMPUTE4(Aa0, Aa1, Ga0, Ga1, 0)
  COMPUTE4(Ab0, Ab1, Gb0, Gb1, 128)

  // stash partials: D rows f = 4*kg + r (+16 for acc1), col i = li; den replicated
#pragma unroll
  for (int r = 0; r < 4; ++r) {
    dpart[wv][4 * kg + r][li]      = acc0[r];
    dpart[wv][16 + 4 * kg + r][li] = acc1[r];
  }
  if (lane < 16) denp[wv][lane] = accd[0];
  __syncthreads();

  // combine 4 j-partials, normalize, LeakyReLU, store
  for (int o = t; o < 512; o += 256) {
    const int f = o & 31, ii = o >> 5;
    const float s  = dpart[0][f][ii] + dpart[1][f][ii]
                   + dpart[2][f][ii] + dpart[3][f][ii];
    const float dn = denp[0][ii] + denp[1][ii] + denp[2][ii] + denp[3][ii];
    float v = s / dn;
    v = fmaxf(v, NSL * v);
    out[((size_t)(b * N_ + i0 + ii)) * FOUT + head * ND + f] = v;
  }
}

extern "C" void kernel_launch(void* const* d_in, const int* in_sizes, int n_in,
                              void* d_out, int out_size, void* d_ws, size_t ws_size,
                              hipStream_t stream) {
  const float* h     = (const float*)d_in[0];
  const int*   adj   = (const int*)d_in[1];
  const float* W     = (const float*)d_in[2];
  const float* a_vec = (const float*)d_in[3];
  float* out = (float*)d_out;

  _Float16* g16 = (_Float16*)d_ws;                         // B*NH*ND*N halves (2 MB)
  float* elt = (float*)(g16 + (size_t)B_ * NH * ND * N_);  // 32768 f
  float* ert = elt + (size_t)B_ * NH * N_;                 // 32768 f

  gat_k1<<<(B_ * N_) / 16, 256, 0, stream>>>(h, W, a_vec, g16, elt, ert);
  gat_k3<<<B_ * NH * (N_ / 16), 256, 0, stream>>>(adj, g16, elt, ert, out);
}